// Round 8
// baseline (159.414 us; speedup 1.0000x reference)
//
#include <hip/hip_runtime.h>
#include <math.h>

#define N_ 16
#define T_ 8192
#define C_ 128
#define K_ 64

// ws layout in floats
#define WS_VLAD 0              // N*K*C = 131072
#define WS_ASUM 131072         // N*K
#define WS_GSUM 132096         // N
#define WS_ZEND 132608
#define WS_RNORM 132608        // N*T floats -> ends at 263680
#define WS_W2F   263680        // 4096 floats (8192 bf16 = w2 fragment table)
#define WS_P1    267776        // 512 floats (wa|wb|wc|sb, each [128])
#define WS_PART  268288        // N*BPN*K*C floats (per-block partials)

typedef __attribute__((ext_vector_type(8))) short short8;
typedef __attribute__((ext_vector_type(4))) float f32x4;

__device__ __forceinline__ uint bfr(float f) {          // fp32 -> bf16 (RNE)
    uint u = __float_as_uint(f);
    return (u + 0x7fffu + ((u >> 16) & 1u)) >> 16;
}

__global__ void zero_ws(float* ws) {
    int i = blockIdx.x * 256 + threadIdx.x;
    if (i < WS_ZEND) ws[i] = 0.0f;
}

// Precompute constant tables, laid out for coalesced loads in main_k.
__global__ void setup_k(const float* __restrict__ conv1_w,
                        const float* __restrict__ bn1_g, const float* __restrict__ bn1_b,
                        const float* __restrict__ bn1_m, const float* __restrict__ bn1_v,
                        const float* __restrict__ conv2_w,
                        const float* __restrict__ bn2_g, const float* __restrict__ bn2_v,
                        float* __restrict__ ws) {
    const int tid = threadIdx.x;
    // w2 fragment table: idx = ((m*4+q)*64 + lane)*8 + j
    ushort* w2t = (ushort*)(ws + WS_W2F);
    for (int idx = tid; idx < 8192; idx += 256) {
        int j = idx & 7;
        int lane = (idx >> 3) & 63;
        int mq = idx >> 9;                  // 0..15
        int m = mq >> 2, q = mq & 3;
        int fr = lane & 15, fg = lane >> 4;
        int k = m * 16 + fr;
        float sck = bn2_g[k] * rsqrtf(bn2_v[k] + 1e-5f);
        float v = conv2_w[k * C_ + q * 32 + fg * 8 + j] * sck;
        w2t[idx] = (ushort)bfr(v);
    }
    // conv1/bn1 folded params, [param][c]
    for (int c = tid; c < C_; c += 256) {
        float s1 = bn1_g[c] * rsqrtf(bn1_v[c] + 1e-5f);
        ws[WS_P1 + c]       = conv1_w[c * 9 + 1] * s1;
        ws[WS_P1 + 128 + c] = conv1_w[c * 9 + 4] * s1;
        ws[WS_P1 + 256 + c] = conv1_w[c * 9 + 7] * s1;
        ws[WS_P1 + 384 + c] = bn1_b[c] - bn1_m[c] * s1;
    }
}

// 1 / max(||x[n,t,:]||, 1e-12), one wave per (n,t) row
__global__ void rnorm_k(const float* __restrict__ x, float* __restrict__ ws) {
    int row = blockIdx.x * 4 + (threadIdx.x >> 6);
    int lane = threadIdx.x & 63;
    const float* xr = x + (size_t)row * C_;
    float a = xr[lane], b = xr[lane + 64];
    float ss = a * a + b * b;
#pragma unroll
    for (int m = 1; m < 64; m <<= 1) ss += __shfl_xor(ss, m, 64);
    if (lane == 0) ws[WS_RNORM + row] = 1.0f / fmaxf(sqrtf(ss), 1e-12f);
}

// Fused: normalize -> dwconv3+bn1+relu -> logits (MFMA) -> bn2+relu+mask
// -> softmax -> vlad GEMM (MFMA, bf16 a/xn + ones-column asum) -> partial store.
// SUP=32 (4 waves x TILE=8); LDS tiles t-minor in 16B chunks, row stride 5
// chunks (80B): chunk index = row*5 + j -> (row*5+j)%8 spreads all 8 groups.
template<int BPN_V, int TPB_V>
__global__ __launch_bounds__(256, 3) void main_k(
    const float* __restrict__ x,
    const float* __restrict__ conv2_b,
    const float* __restrict__ bn2_g, const float* __restrict__ bn2_b,
    const float* __restrict__ bn2_m, const float* __restrict__ bn2_v,
    const int* __restrict__ length,
    float* __restrict__ ws) {

    __shared__ __align__(16) ushort h_s[4][8 * 136];   // per-wave [8t][136] 8704 B
    __shared__ __align__(16) uint4 xn4[144 * 5];       // rows 0..127 xn, 128..143 ones/zero cols
    __shared__ __align__(16) uint4 ab[64 * 5];         // a rows
    __shared__ float rn_lds[TPB_V + 2];

    const int tid = threadIdx.x;
    const int lane = tid & 63;
    const int w = tid >> 6;
    const int fr = lane & 15, fg = lane >> 4;
    const int n = blockIdx.x / BPN_V;
    const int chunk = blockIdx.x % BPN_V;
    const int tb = chunk * TPB_V;
    const float* xb = x + (size_t)n * T_ * C_;
    const float* rng = ws + WS_RNORM + (size_t)n * T_;
    const int L = length[n];

    for (int i = tid; i < TPB_V + 2; i += 256) {
        int t = tb - 1 + i;
        rn_lds[i] = (t >= 0 && t < T_) ? rng[t] : 0.f;
    }
    // static ones/zero columns for the asum trick (rows 128..143, all 4 chunks)
    if (tid < 64) {
        int r = 128 + (tid >> 2), j = tid & 3;
        uint f = (r == 128) ? 0x3F803F80u : 0u;        // bf16 1.0 pairs / zeros
        uint4 v; v.x = f; v.y = f; v.z = f; v.w = f;
        xn4[r * 5 + j] = v;
    }

    // conv1/bn1 folded params for c = lane, lane+64
    float wa[2], wbv[2], wcv[2], sbv[2];
#pragma unroll
    for (int p = 0; p < 2; ++p) {
        int c = lane + p * 64;
        wa[p]  = ws[WS_P1 + c];
        wbv[p] = ws[WS_P1 + 128 + c];
        wcv[p] = ws[WS_P1 + 256 + c];
        sbv[p] = ws[WS_P1 + 384 + c];
    }

    // w2 A-fragments from precomputed table (coalesced b128 loads)
    const ushort* w2t = (const ushort*)(ws + WS_W2F);
    short8 w2h[4][4];
#pragma unroll
    for (int m = 0; m < 4; ++m)
#pragma unroll
        for (int q = 0; q < 4; ++q)
            w2h[m][q] = *(const short8*)&w2t[((m * 4 + q) * 64 + lane) * 8];

    // bias in softmax register layout: k = m*16 + fg*4 + r
    float sh2r[16];
#pragma unroll
    for (int m = 0; m < 4; ++m)
#pragma unroll
        for (int r = 0; r < 4; ++r) {
            int k = m * 16 + fg * 4 + r;
            float s = bn2_g[k] * rsqrtf(bn2_v[k] + 1e-5f);
            sh2r[m * 4 + r] = s * conv2_b[k] + bn2_b[k] - bn2_m[k] * s;
        }

    f32x4 accB[9];
#pragma unroll
    for (int cb = 0; cb < 9; ++cb) accB[cb] = (f32x4){0.f, 0.f, 0.f, 0.f};

    __syncthreads();

    for (int s = 0; s < TPB_V / 32; ++s) {
        const int t0 = tb + s * 32 + w * 8;
        const bool full = (t0 < L);
        const int tl0 = t0 - tb;
        ushort* hw = h_s[w];

        // ---- A1: rolling 3-tap conv along t (8 steps), lane = channel ----
#pragma unroll
        for (int p = 0; p < 2; ++p) {
            const int c = lane + p * 64;
            float xnm = 0.f;
            if (t0 > 0) xnm = xb[(size_t)(t0 - 1) * C_ + c] * rn_lds[tl0];
            float xnc = xb[(size_t)t0 * C_ + c] * rn_lds[tl0 + 1];
            uint pk[4];
#pragma unroll
            for (int tl = 0; tl < 8; ++tl) {
                int tn = t0 + tl + 1;
                float xnp = 0.f;
                if (tn < T_) xnp = xb[(size_t)tn * C_ + c] * rn_lds[tl0 + tl + 2];
                if (full) {
                    float h = fmaxf(0.f, xnm * wa[p] + xnc * wbv[p] + xnp * wcv[p] + sbv[p]);
                    hw[tl * 136 + c] = (ushort)bfr(h);
                }
                uint b = bfr(xnc);
                if (tl & 1) pk[tl >> 1] |= b << 16; else pk[tl >> 1] = b;
                xnm = xnc; xnc = xnp;
            }
            uint4 v4; v4.x = pk[0]; v4.y = pk[1]; v4.z = pk[2]; v4.w = pk[3];
            xn4[c * 5 + w] = v4;
        }

        if (full) {
            // ---- logits MFMA: S[k][t] = sum_c w2'[k][c] h[t][c] (t cols 0..7 dup'd) ----
            f32x4 accL[4];
#pragma unroll
            for (int m = 0; m < 4; ++m) accL[m] = (f32x4){0.f, 0.f, 0.f, 0.f};
            const ushort* hb = hw + (fr & 7) * 136 + fg * 8;
#pragma unroll
            for (int q = 0; q < 4; ++q) {
                short8 hf = *(const short8*)(hb + q * 32);
                accL[0] = __builtin_amdgcn_mfma_f32_16x16x32_bf16(w2h[0][q], hf, accL[0], 0, 0, 0);
                accL[1] = __builtin_amdgcn_mfma_f32_16x16x32_bf16(w2h[1][q], hf, accL[1], 0, 0, 0);
                accL[2] = __builtin_amdgcn_mfma_f32_16x16x32_bf16(w2h[2][q], hf, accL[2], 0, 0, 0);
                accL[3] = __builtin_amdgcn_mfma_f32_16x16x32_bf16(w2h[3][q], hf, accL[3], 0, 0, 0);
            }
            // ---- bn2 + relu + mask + softmax over k (lane column t = t0+fr, fr<8) ----
            if (fr < 8) {
                int t = t0 + fr;
                float v[16];
#pragma unroll
                for (int m = 0; m < 4; ++m)
#pragma unroll
                    for (int r = 0; r < 4; ++r)
                        v[m * 4 + r] = fmaxf(0.f, accL[m][r] + sh2r[m * 4 + r]);
                if (t < L) {
                    float mx = v[0];
#pragma unroll
                    for (int i = 1; i < 16; ++i) mx = fmaxf(mx, v[i]);
                    mx = fmaxf(mx, __shfl_xor(mx, 16, 64));
                    mx = fmaxf(mx, __shfl_xor(mx, 32, 64));
                    float se = 0.f;
#pragma unroll
                    for (int i = 0; i < 16; ++i) { v[i] = __expf(v[i] - mx); se += v[i]; }
                    se += __shfl_xor(se, 16, 64);
                    se += __shfl_xor(se, 32, 64);
                    float inv = 1.0f / se;
#pragma unroll
                    for (int i = 0; i < 16; ++i) v[i] *= inv;
                } else {
#pragma unroll
                    for (int i = 0; i < 16; ++i) v[i] = 0.015625f;
                }
#pragma unroll
                for (int m = 0; m < 4; ++m)
#pragma unroll
                    for (int r = 0; r < 4; ++r) {
                        int k = m * 16 + fg * 4 + r;
                        ((ushort*)&ab[k * 5 + w])[fr] = (ushort)bfr(v[m * 4 + r]);
                    }
            }
        } else {
            // fully masked tile: a = 1/64 (bf16 exact), all 64 k rows, this wave's chunk
            uint4 ones;
            ones.x = ones.y = ones.z = ones.w = 0x3C803C80u;
            ab[lane * 5 + w] = ones;
        }
        __syncthreads();

        // ---- phase B: vlad GEMM + ones-column asum. wave w owns k-block w ----
        {
            int ar = w * 16 + fr;
            short8 af = *(const short8*)&ab[ar * 5 + fg];
#pragma unroll
            for (int cb = 0; cb < 9; ++cb) {
                int cr = cb * 16 + fr;
                short8 bfv = *(const short8*)&xn4[cr * 5 + fg];
                accB[cb] = __builtin_amdgcn_mfma_f32_16x16x32_bf16(af, bfv, accB[cb], 0, 0, 0);
            }
        }
        __syncthreads();
    }

    // ---- private partial store (no vlad atomics) ----
    float* part = ws + WS_PART + (size_t)(n * BPN_V + chunk) * (K_ * C_);
#pragma unroll
    for (int cb = 0; cb < 8; ++cb)
#pragma unroll
        for (int r = 0; r < 4; ++r)
            part[(w * 16 + fg * 4 + r) * C_ + cb * 16 + fr] = accB[cb][r];
    // asum from the ones-column (col 128 lives in fr==0 lanes)
    if (fr == 0) {
#pragma unroll
        for (int r = 0; r < 4; ++r)
            atomicAdd(&ws[WS_ASUM + n * K_ + w * 16 + fg * 4 + r], accB[8][r]);
    }
}

// vlad[n][k][c] = sum over BPN per-block partials
template<int BPN_V>
__global__ void reduce_k(float* __restrict__ ws) {
    int idx = blockIdx.x * 256 + threadIdx.x;      // < N*K*C
    int n = idx >> 13;
    const float* p = ws + WS_PART + (size_t)n * BPN_V * (K_ * C_) + (idx & 8191);
    float s = 0.f;
#pragma unroll 8
    for (int b = 0; b < BPN_V; ++b) s += p[(size_t)b * (K_ * C_)];
    ws[WS_VLAD + idx] = s;
}

// per (n,k) row: subtract asum*centroid, intra-L2-normalize, accumulate gsum
__global__ void finalize_k(const float* __restrict__ cent, float* __restrict__ ws,
                           float* __restrict__ out) {
    int row = blockIdx.x * 4 + (threadIdx.x >> 6);  // n*64 + k
    int lane = threadIdx.x & 63;
    int n = row >> 6, k = row & 63;
    const float* v = ws + WS_VLAD + (size_t)row * C_;
    float as = ws[WS_ASUM + row];
    float y0 = v[lane] - as * cent[k * C_ + lane];
    float y1 = v[lane + 64] - as * cent[k * C_ + lane + 64];
    float ss = y0 * y0 + y1 * y1;
#pragma unroll
    for (int m = 1; m < 64; m <<= 1) ss += __shfl_xor(ss, m, 64);
    float rs = 1.0f / fmaxf(sqrtf(ss), 1e-12f);
    out[(size_t)row * C_ + lane] = y0 * rs;
    out[(size_t)row * C_ + lane + 64] = y1 * rs;
    if (lane == 0) atomicAdd(&ws[WS_GSUM + n], ss * rs * rs);
}

__global__ void gscale_k(float* __restrict__ out, const float* __restrict__ ws) {
    int idx = blockIdx.x * 256 + threadIdx.x;  // < N*K*C
    int n = idx >> 13;
    float g = ws[WS_GSUM + n];
    out[idx] *= 1.0f / fmaxf(sqrtf(g), 1e-12f);
}

extern "C" void kernel_launch(void* const* d_in, const int* in_sizes, int n_in,
                              void* d_out, int out_size, void* d_ws, size_t ws_size,
                              hipStream_t stream) {
    const float* x       = (const float*)d_in[0];
    const float* conv1_w = (const float*)d_in[1];
    const float* bn1_g   = (const float*)d_in[2];
    const float* bn1_b   = (const float*)d_in[3];
    const float* bn1_m   = (const float*)d_in[4];
    const float* bn1_v   = (const float*)d_in[5];
    const float* conv2_w = (const float*)d_in[6];
    const float* conv2_b = (const float*)d_in[7];
    const float* bn2_g   = (const float*)d_in[8];
    const float* bn2_b   = (const float*)d_in[9];
    const float* bn2_m   = (const float*)d_in[10];
    const float* bn2_v   = (const float*)d_in[11];
    const float* cent    = (const float*)d_in[12];
    const int*   length  = (const int*)d_in[13];
    float* out = (float*)d_out;
    float* ws  = (float*)d_ws;

    zero_ws<<<(WS_ZEND + 255) / 256, 256, 0, stream>>>(ws);
    setup_k<<<1, 256, 0, stream>>>(conv1_w, bn1_g, bn1_b, bn1_m, bn1_v,
                                   conv2_w, bn2_g, bn2_v, ws);
    rnorm_k<<<N_ * T_ / 4, 256, 0, stream>>>(x, ws);

    const size_t need_big = ((size_t)WS_PART + (size_t)N_ * 64 * K_ * C_) * 4;
    if (ws_size >= need_big) {
        main_k<64, 128><<<N_ * 64, 256, 0, stream>>>(x, conv2_b, bn2_g, bn2_b,
                                                     bn2_m, bn2_v, length, ws);
        reduce_k<64><<<(N_ * K_ * C_) / 256, 256, 0, stream>>>(ws);
    } else {
        main_k<32, 256><<<N_ * 32, 256, 0, stream>>>(x, conv2_b, bn2_g, bn2_b,
                                                     bn2_m, bn2_v, length, ws);
        reduce_k<32><<<(N_ * K_ * C_) / 256, 256, 0, stream>>>(ws);
    }
    finalize_k<<<(N_ * K_) / 4, 256, 0, stream>>>(cent, ws, out);
    gscale_k<<<(N_ * K_ * C_) / 256, 256, 0, stream>>>(out, ws);
}

// Round 9
// 128.990 us; speedup vs baseline: 1.2359x; 1.2359x over previous
//
#include <hip/hip_runtime.h>
#include <math.h>

#define N_ 16
#define T_ 8192
#define C_ 128
#define K_ 64

#define TPB_A 128      // t per assign block
#define BPN_A 64       // assign blocks per n
#define TCH 256        // t per vlad block
#define NCH 32         // vlad chunks per n

// ws layout in floats (total 8656896 floats = 34.63 MB, proven available in r8)
#define WS_VLAD 0              // N*K*C = 131072
#define WS_ASUM 131072         // N*K
#define WS_GSUM 132096         // N
#define WS_ZEND 132608
#define WS_RNORM 132608        // N*T -> 263680
#define WS_W2F   263680        // 4096 floats (8192 bf16 w2 fragment table)
#define WS_P1    267776        // 512 floats
#define WS_AG    268288        // a bf16: N*T*K ushorts = 4194304 floats -> 4462592
#define WS_PART  4462592       // N*NCH*K*C floats = 4194304 -> 8656896

typedef __attribute__((ext_vector_type(8))) short short8;
typedef __attribute__((ext_vector_type(4))) float f32x4;

__device__ __forceinline__ uint bfr(float f) {          // fp32 -> bf16 (RNE)
    uint u = __float_as_uint(f);
    return (u + 0x7fffu + ((u >> 16) & 1u)) >> 16;
}

__global__ void zero_ws(float* ws) {
    int i = blockIdx.x * 256 + threadIdx.x;
    if (i < WS_ZEND) ws[i] = 0.0f;
}

// Precompute constant tables, laid out for coalesced loads.
__global__ void setup_k(const float* __restrict__ conv1_w,
                        const float* __restrict__ bn1_g, const float* __restrict__ bn1_b,
                        const float* __restrict__ bn1_m, const float* __restrict__ bn1_v,
                        const float* __restrict__ conv2_w,
                        const float* __restrict__ bn2_g, const float* __restrict__ bn2_v,
                        float* __restrict__ ws) {
    const int tid = threadIdx.x;
    ushort* w2t = (ushort*)(ws + WS_W2F);
    for (int idx = tid; idx < 8192; idx += 256) {
        int j = idx & 7;
        int lane = (idx >> 3) & 63;
        int mq = idx >> 9;
        int m = mq >> 2, q = mq & 3;
        int fr = lane & 15, fg = lane >> 4;
        int k = m * 16 + fr;
        float sck = bn2_g[k] * rsqrtf(bn2_v[k] + 1e-5f);
        float v = conv2_w[k * C_ + q * 32 + fg * 8 + j] * sck;
        w2t[idx] = (ushort)bfr(v);
    }
    for (int c = tid; c < C_; c += 256) {
        float s1 = bn1_g[c] * rsqrtf(bn1_v[c] + 1e-5f);
        ws[WS_P1 + c]       = conv1_w[c * 9 + 1] * s1;
        ws[WS_P1 + 128 + c] = conv1_w[c * 9 + 4] * s1;
        ws[WS_P1 + 256 + c] = conv1_w[c * 9 + 7] * s1;
        ws[WS_P1 + 384 + c] = bn1_b[c] - bn1_m[c] * s1;
    }
}

// 1 / max(||x[n,t,:]||, 1e-12), one wave per (n,t) row
__global__ void rnorm_k(const float* __restrict__ x, float* __restrict__ ws) {
    int row = blockIdx.x * 4 + (threadIdx.x >> 6);
    int lane = threadIdx.x & 63;
    const float* xr = x + (size_t)row * C_;
    float a = xr[lane], b = xr[lane + 64];
    float ss = a * a + b * b;
#pragma unroll
    for (int m = 1; m < 64; m <<= 1) ss += __shfl_xor(ss, m, 64);
    if (lane == 0) ws[WS_RNORM + row] = 1.0f / fmaxf(sqrtf(ss), 1e-12f);
}

// a-production: normalize -> dwconv3+bn1+relu -> logits (MFMA) -> softmax
// -> write a (bf16) to global in fragment-ready t-minor tiles [tc][64k][32t].
// Fully-masked waves write the 1/64 constant and skip all loads.
__global__ __launch_bounds__(256, 4) void assign_k(
    const float* __restrict__ x,
    const float* __restrict__ conv2_b,
    const float* __restrict__ bn2_g, const float* __restrict__ bn2_b,
    const float* __restrict__ bn2_m, const float* __restrict__ bn2_v,
    const int* __restrict__ length,
    float* __restrict__ ws) {

    __shared__ __align__(16) ushort h_s[4][8 * 136];     // per-wave [8t][136c]
    __shared__ __align__(16) uint4 ab[2][64 * 5];        // a rows, dbuf, 5-chunk stride
    __shared__ float rn_lds[TPB_A + 2];

    const int tid = threadIdx.x;
    const int lane = tid & 63;
    const int w = tid >> 6;
    const int fr = lane & 15, fg = lane >> 4;
    const int n = blockIdx.x >> 6;
    const int tb = (blockIdx.x & (BPN_A - 1)) * TPB_A;
    const float* xb = x + (size_t)n * T_ * C_;
    const float* rng = ws + WS_RNORM + (size_t)n * T_;
    const int L = length[n];

    for (int i = tid; i < TPB_A + 2; i += 256) {
        int t = tb - 1 + i;
        rn_lds[i] = (t >= 0 && t < T_) ? rng[t] : 0.f;
    }

    float wa[2], wbv[2], wcv[2], sbv[2];
#pragma unroll
    for (int p = 0; p < 2; ++p) {
        int c = lane + p * 64;
        wa[p]  = ws[WS_P1 + c];
        wbv[p] = ws[WS_P1 + 128 + c];
        wcv[p] = ws[WS_P1 + 256 + c];
        sbv[p] = ws[WS_P1 + 384 + c];
    }

    const ushort* w2t = (const ushort*)(ws + WS_W2F);
    short8 w2h[4][4];
#pragma unroll
    for (int m = 0; m < 4; ++m)
#pragma unroll
        for (int q = 0; q < 4; ++q)
            w2h[m][q] = *(const short8*)&w2t[((m * 4 + q) * 64 + lane) * 8];

    float sh2r[16];
#pragma unroll
    for (int m = 0; m < 4; ++m)
#pragma unroll
        for (int r = 0; r < 4; ++r) {
            int k = m * 16 + fg * 4 + r;
            float s = bn2_g[k] * rsqrtf(bn2_v[k] + 1e-5f);
            sh2r[m * 4 + r] = s * conv2_b[k] + bn2_b[k] - bn2_m[k] * s;
        }

    ushort* ag = (ushort*)(ws + WS_AG) + (size_t)n * T_ * K_;
    int buf = 0;
    __syncthreads();

    for (int s = 0; s < TPB_A / 32; ++s) {
        const int t0 = tb + s * 32 + w * 8;
        const int tl0 = t0 - tb;

        if (t0 < L) {
            // ---- A1: rolling 3-tap conv along t (h only) ----
            ushort* hw = h_s[w];
#pragma unroll
            for (int p = 0; p < 2; ++p) {
                const int c = lane + p * 64;
                float xnm = 0.f;
                if (t0 > 0) xnm = xb[(size_t)(t0 - 1) * C_ + c] * rn_lds[tl0];
                float xnc = xb[(size_t)t0 * C_ + c] * rn_lds[tl0 + 1];
#pragma unroll
                for (int tl = 0; tl < 8; ++tl) {
                    int tn = t0 + tl + 1;
                    float xnp = 0.f;
                    if (tn < T_) xnp = xb[(size_t)tn * C_ + c] * rn_lds[tl0 + tl + 2];
                    float h = fmaxf(0.f, xnm * wa[p] + xnc * wbv[p] + xnp * wcv[p] + sbv[p]);
                    hw[tl * 136 + c] = (ushort)bfr(h);
                    xnm = xnc; xnc = xnp;
                }
            }
            // ---- logits MFMA ----
            f32x4 accL[4];
#pragma unroll
            for (int m = 0; m < 4; ++m) accL[m] = (f32x4){0.f, 0.f, 0.f, 0.f};
            const ushort* hb = hw + (fr & 7) * 136 + fg * 8;
#pragma unroll
            for (int q = 0; q < 4; ++q) {
                short8 hf = *(const short8*)(hb + q * 32);
                accL[0] = __builtin_amdgcn_mfma_f32_16x16x32_bf16(w2h[0][q], hf, accL[0], 0, 0, 0);
                accL[1] = __builtin_amdgcn_mfma_f32_16x16x32_bf16(w2h[1][q], hf, accL[1], 0, 0, 0);
                accL[2] = __builtin_amdgcn_mfma_f32_16x16x32_bf16(w2h[2][q], hf, accL[2], 0, 0, 0);
                accL[3] = __builtin_amdgcn_mfma_f32_16x16x32_bf16(w2h[3][q], hf, accL[3], 0, 0, 0);
            }
            // ---- bn2 + relu + mask + softmax over k (lane column t = t0+fr, fr<8) ----
            if (fr < 8) {
                int t = t0 + fr;
                float v[16];
#pragma unroll
                for (int m = 0; m < 4; ++m)
#pragma unroll
                    for (int r = 0; r < 4; ++r)
                        v[m * 4 + r] = fmaxf(0.f, accL[m][r] + sh2r[m * 4 + r]);
                if (t < L) {
                    float mx = v[0];
#pragma unroll
                    for (int i = 1; i < 16; ++i) mx = fmaxf(mx, v[i]);
                    mx = fmaxf(mx, __shfl_xor(mx, 16, 64));
                    mx = fmaxf(mx, __shfl_xor(mx, 32, 64));
                    float se = 0.f;
#pragma unroll
                    for (int i = 0; i < 16; ++i) { v[i] = __expf(v[i] - mx); se += v[i]; }
                    se += __shfl_xor(se, 16, 64);
                    se += __shfl_xor(se, 32, 64);
                    float inv = 1.0f / se;
#pragma unroll
                    for (int i = 0; i < 16; ++i) v[i] *= inv;
                } else {
#pragma unroll
                    for (int i = 0; i < 16; ++i) v[i] = 0.015625f;
                }
#pragma unroll
                for (int m = 0; m < 4; ++m)
#pragma unroll
                    for (int r = 0; r < 4; ++r) {
                        int k = m * 16 + fg * 4 + r;
                        ((ushort*)&ab[buf][k * 5 + w])[fr] = (ushort)bfr(v[m * 4 + r]);
                    }
            }
        } else {
            // fully masked: a = 1/64 exactly, no loads
            uint4 ones;
            ones.x = ones.y = ones.z = ones.w = 0x3C803C80u;
            ab[buf][lane * 5 + w] = ones;
        }
        __syncthreads();

        // ---- copy-out a tile [64k][32t] (4 KB, fully coalesced) ----
        {
            uint4 v = ab[buf][(tid >> 2) * 5 + (tid & 3)];
            *((uint4*)(ag + (size_t)(tb / 32 + s) * 2048) + tid) = v;
        }
        buf ^= 1;
    }
}

// vlad GEMM: per (n, 256-t chunk): stage xn (x * rn -> bf16 t-minor LDS, + ones
// row for asum), read a fragments from global, MFMA-accumulate, store partials.
__global__ __launch_bounds__(256, 4) void vlad_k(
    const float* __restrict__ x, float* __restrict__ ws) {

    __shared__ __align__(16) uint4 xn4[144 * 5];   // rows 0..127 xn, 128 ones, 129..143 zero
    __shared__ float rn_lds[TCH];

    const int tid = threadIdx.x;
    const int lane = tid & 63;
    const int w = tid >> 6;
    const int fr = lane & 15, fg = lane >> 4;
    const int n = blockIdx.x >> 5;
    const int chunk = blockIdx.x & (NCH - 1);
    const int tb = chunk * TCH;
    const float* xb = x + (size_t)n * T_ * C_;
    const float* rng = ws + WS_RNORM + (size_t)n * T_;

    for (int i = tid; i < TCH; i += 256) rn_lds[i] = rng[tb + i];
    if (tid < 64) {
        int r = 128 + (tid >> 2), j = tid & 3;
        uint f = (r == 128) ? 0x3F803F80u : 0u;
        uint4 v; v.x = f; v.y = f; v.z = f; v.w = f;
        xn4[r * 5 + j] = v;
    }

    const ushort* ag = (const ushort*)(ws + WS_AG) + (size_t)n * T_ * K_;

    f32x4 accB[9];
#pragma unroll
    for (int cb = 0; cb < 9; ++cb) accB[cb] = (f32x4){0.f, 0.f, 0.f, 0.f};

    __syncthreads();

    for (int st = 0; st < TCH / 32; ++st) {
        const int t0 = tb + st * 32;
        const int tw = t0 + w * 8;
        // ---- stage xn t-minor (wave w owns t-slice w) ----
#pragma unroll
        for (int p = 0; p < 2; ++p) {
            const int c = lane + p * 64;
            uint pk[4];
#pragma unroll
            for (int tl = 0; tl < 8; ++tl) {
                float xv = xb[(size_t)(tw + tl) * C_ + c] * rn_lds[tw + tl - tb];
                uint b = bfr(xv);
                if (tl & 1) pk[tl >> 1] |= b << 16; else pk[tl >> 1] = b;
            }
            uint4 v4; v4.x = pk[0]; v4.y = pk[1]; v4.z = pk[2]; v4.w = pk[3];
            xn4[c * 5 + w] = v4;
        }
        __syncthreads();
        // ---- a fragment from global (contiguous 1 KB per wave) + 9 MFMA ----
        short8 af = *(const short8*)(ag + (size_t)(t0 >> 5) * 2048 + (w * 16 + fr) * 32 + fg * 8);
#pragma unroll
        for (int cb = 0; cb < 9; ++cb) {
            short8 bfv = *(const short8*)&xn4[(cb * 16 + fr) * 5 + fg];
            accB[cb] = __builtin_amdgcn_mfma_f32_16x16x32_bf16(af, bfv, accB[cb], 0, 0, 0);
        }
        __syncthreads();
    }

    float* part = ws + WS_PART + (size_t)(n * NCH + chunk) * (K_ * C_);
#pragma unroll
    for (int cb = 0; cb < 8; ++cb)
#pragma unroll
        for (int r = 0; r < 4; ++r)
            part[(w * 16 + fg * 4 + r) * C_ + cb * 16 + fr] = accB[cb][r];
    if (fr == 0) {
#pragma unroll
        for (int r = 0; r < 4; ++r)
            atomicAdd(&ws[WS_ASUM + n * K_ + w * 16 + fg * 4 + r], accB[8][r]);
    }
}

// vlad[n][k][c] = sum over NCH per-chunk partials
__global__ void reduce_k(float* __restrict__ ws) {
    int idx = blockIdx.x * 256 + threadIdx.x;      // < N*K*C
    int n = idx >> 13;
    const float* p = ws + WS_PART + (size_t)n * NCH * (K_ * C_) + (idx & 8191);
    float s = 0.f;
#pragma unroll 8
    for (int b = 0; b < NCH; ++b) s += p[(size_t)b * (K_ * C_)];
    ws[WS_VLAD + idx] = s;
}

// per (n,k) row: subtract asum*centroid, intra-L2-normalize, accumulate gsum
__global__ void finalize_k(const float* __restrict__ cent, float* __restrict__ ws,
                           float* __restrict__ out) {
    int row = blockIdx.x * 4 + (threadIdx.x >> 6);  // n*64 + k
    int lane = threadIdx.x & 63;
    int n = row >> 6, k = row & 63;
    const float* v = ws + WS_VLAD + (size_t)row * C_;
    float as = ws[WS_ASUM + row];
    float y0 = v[lane] - as * cent[k * C_ + lane];
    float y1 = v[lane + 64] - as * cent[k * C_ + lane + 64];
    float ss = y0 * y0 + y1 * y1;
#pragma unroll
    for (int m = 1; m < 64; m <<= 1) ss += __shfl_xor(ss, m, 64);
    float rs = 1.0f / fmaxf(sqrtf(ss), 1e-12f);
    out[(size_t)row * C_ + lane] = y0 * rs;
    out[(size_t)row * C_ + lane + 64] = y1 * rs;
    if (lane == 0) atomicAdd(&ws[WS_GSUM + n], ss * rs * rs);
}

__global__ void gscale_k(float* __restrict__ out, const float* __restrict__ ws) {
    int idx = blockIdx.x * 256 + threadIdx.x;  // < N*K*C
    int n = idx >> 13;
    float g = ws[WS_GSUM + n];
    out[idx] *= 1.0f / fmaxf(sqrtf(g), 1e-12f);
}

extern "C" void kernel_launch(void* const* d_in, const int* in_sizes, int n_in,
                              void* d_out, int out_size, void* d_ws, size_t ws_size,
                              hipStream_t stream) {
    const float* x       = (const float*)d_in[0];
    const float* conv1_w = (const float*)d_in[1];
    const float* bn1_g   = (const float*)d_in[2];
    const float* bn1_b   = (const float*)d_in[3];
    const float* bn1_m   = (const float*)d_in[4];
    const float* bn1_v   = (const float*)d_in[5];
    const float* conv2_w = (const float*)d_in[6];
    const float* conv2_b = (const float*)d_in[7];
    const float* bn2_g   = (const float*)d_in[8];
    const float* bn2_b   = (const float*)d_in[9];
    const float* bn2_m   = (const float*)d_in[10];
    const float* bn2_v   = (const float*)d_in[11];
    const float* cent    = (const float*)d_in[12];
    const int*   length  = (const int*)d_in[13];
    float* out = (float*)d_out;
    float* ws  = (float*)d_ws;

    zero_ws<<<(WS_ZEND + 255) / 256, 256, 0, stream>>>(ws);
    setup_k<<<1, 256, 0, stream>>>(conv1_w, bn1_g, bn1_b, bn1_m, bn1_v,
                                   conv2_w, bn2_g, bn2_v, ws);
    rnorm_k<<<N_ * T_ / 4, 256, 0, stream>>>(x, ws);
    assign_k<<<N_ * BPN_A, 256, 0, stream>>>(x, conv2_b, bn2_g, bn2_b,
                                             bn2_m, bn2_v, length, ws);
    vlad_k<<<N_ * NCH, 256, 0, stream>>>(x, ws);
    reduce_k<<<(N_ * K_ * C_) / 256, 256, 0, stream>>>(ws);
    finalize_k<<<(N_ * K_) / 4, 256, 0, stream>>>(cent, ws, out);
    gscale_k<<<(N_ * K_ * C_) / 256, 256, 0, stream>>>(out, ws);
}

// Round 11
// 100.395 us; speedup vs baseline: 1.5879x; 1.2848x over previous
//
#include <hip/hip_runtime.h>
#include <math.h>

#define N_ 16
#define T_ 8192
#define C_ 128
#define K_ 64

#define TPB_A 128      // t per assign block
#define BPN_A 64       // assign blocks per n
#define TCH 256        // t per vlad block
#define NCH 32         // vlad chunks per n

// ws layout in floats (total 8656896 floats = 34.63 MB, proven available)
#define WS_VLAD 0              // N*K*C = 131072
#define WS_ASUM 131072         // N*K
#define WS_GSUM 132096         // N
#define WS_ZEND 132608
#define WS_RNORM 132608        // N*T -> 263680
#define WS_W2F   263680        // 4096 floats (8192 bf16 w2 fragment table)
#define WS_P1    267776        // 512 floats
#define WS_AG    268288        // a bf16: N*T*K ushorts -> 4462592
#define WS_PART  4462592       // N*NCH*K*C floats -> 8656896

typedef __attribute__((ext_vector_type(8))) short short8;
typedef __attribute__((ext_vector_type(4))) float f32x4;

__device__ __forceinline__ uint bfr(float f) {          // fp32 -> bf16 (RNE)
    uint u = __float_as_uint(f);
    return (u + 0x7fffu + ((u >> 16) & 1u)) >> 16;
}
__device__ __forceinline__ uint pack2(float lo, float hi) {
    return bfr(lo) | (bfr(hi) << 16);
}

__global__ void zero_ws(float* ws) {
    int i = WS_ASUM + blockIdx.x * 256 + threadIdx.x;
    if (i < WS_ZEND) ws[i] = 0.0f;
}

// Precompute constant tables, laid out for coalesced loads.
__global__ void setup_k(const float* __restrict__ conv1_w,
                        const float* __restrict__ bn1_g, const float* __restrict__ bn1_b,
                        const float* __restrict__ bn1_m, const float* __restrict__ bn1_v,
                        const float* __restrict__ conv2_w,
                        const float* __restrict__ bn2_g, const float* __restrict__ bn2_v,
                        float* __restrict__ ws) {
    const int tid = threadIdx.x;
    ushort* w2t = (ushort*)(ws + WS_W2F);
    for (int idx = tid; idx < 8192; idx += 256) {
        int j = idx & 7;
        int lane = (idx >> 3) & 63;
        int mq = idx >> 9;
        int m = mq >> 2, q = mq & 3;
        int fr = lane & 15, fg = lane >> 4;
        int k = m * 16 + fr;
        float sck = bn2_g[k] * rsqrtf(bn2_v[k] + 1e-5f);
        float v = conv2_w[k * C_ + q * 32 + fg * 8 + j] * sck;
        w2t[idx] = (ushort)bfr(v);
    }
    for (int c = tid; c < C_; c += 256) {
        float s1 = bn1_g[c] * rsqrtf(bn1_v[c] + 1e-5f);
        ws[WS_P1 + c]       = conv1_w[c * 9 + 1] * s1;
        ws[WS_P1 + 128 + c] = conv1_w[c * 9 + 4] * s1;
        ws[WS_P1 + 256 + c] = conv1_w[c * 9 + 7] * s1;
        ws[WS_P1 + 384 + c] = bn1_b[c] - bn1_m[c] * s1;
    }
}

// 1 / max(||x[n,t,:]||, 1e-12), one wave per (n,t) row
__global__ void rnorm_k(const float* __restrict__ x, float* __restrict__ ws) {
    int row = blockIdx.x * 4 + (threadIdx.x >> 6);
    int lane = threadIdx.x & 63;
    const float* xr = x + (size_t)row * C_;
    float a = xr[lane], b = xr[lane + 64];
    float ss = a * a + b * b;
#pragma unroll
    for (int m = 1; m < 64; m <<= 1) ss += __shfl_xor(ss, m, 64);
    if (lane == 0) ws[WS_RNORM + row] = 1.0f / fmaxf(sqrtf(ss), 1e-12f);
}

// a-production: normalize -> dwconv3+bn1+relu -> logits (MFMA, w2 in LDS)
// -> softmax -> a tiles [64k][32t] bf16 to global. Fully-masked super-tiles
// are skipped entirely (vlad_k substitutes the 1/64 constant).
__global__ __launch_bounds__(256, 3) void assign_k(
    const float* __restrict__ x,
    const float* __restrict__ conv2_b,
    const float* __restrict__ bn2_g, const float* __restrict__ bn2_b,
    const float* __restrict__ bn2_m, const float* __restrict__ bn2_v,
    const int* __restrict__ length,
    float* __restrict__ ws) {

    __shared__ __align__(16) ushort w2l[8192];           // 16 KB w2 fragments
    __shared__ __align__(16) ushort h_s[4][8 * 136];     // per-wave [8t][136c]
    __shared__ __align__(16) uint4 ab[2][64 * 5];        // a rows, dbuf
    __shared__ float rn_lds[TPB_A + 2];

    const int tid = threadIdx.x;
    const int lane = tid & 63;
    const int w = tid >> 6;
    const int fr = lane & 15, fg = lane >> 4;
    const int n = blockIdx.x >> 6;
    const int tb = (blockIdx.x & (BPN_A - 1)) * TPB_A;
    const float* xb = x + (size_t)n * T_ * C_;
    const float* rng = ws + WS_RNORM + (size_t)n * T_;
    const int L = length[n];

    // coop-load w2 fragment table into LDS (1024 x uint4 = 16 KB)
    {
        const uint4* w2g = (const uint4*)(ws + WS_W2F);
        uint4* w2d = (uint4*)w2l;
#pragma unroll
        for (int i = 0; i < 4; ++i) w2d[tid + i * 256] = w2g[tid + i * 256];
    }
    for (int i = tid; i < TPB_A + 2; i += 256) {
        int t = tb - 1 + i;
        rn_lds[i] = (t >= 0 && t < T_) ? rng[t] : 0.f;
    }

    // conv1/bn1 folded params for the lane's c-pair (c2, c2+1)
    const int c2 = lane * 2;
    float2 wa = *(const float2*)&ws[WS_P1 + c2];
    float2 wb = *(const float2*)&ws[WS_P1 + 128 + c2];
    float2 wc = *(const float2*)&ws[WS_P1 + 256 + c2];
    float2 sb = *(const float2*)&ws[WS_P1 + 384 + c2];

    float sh2r[16];
#pragma unroll
    for (int m = 0; m < 4; ++m)
#pragma unroll
        for (int r = 0; r < 4; ++r) {
            int k = m * 16 + fg * 4 + r;
            float s = bn2_g[k] * rsqrtf(bn2_v[k] + 1e-5f);
            sh2r[m * 4 + r] = s * conv2_b[k] + bn2_b[k] - bn2_m[k] * s;
        }

    ushort* ag = (ushort*)(ws + WS_AG) + (size_t)n * T_ * K_;
    int buf = 0;
    __syncthreads();

    for (int s = 0; s < TPB_A / 32; ++s) {
        const int tbs = tb + s * 32;
        if (tbs >= L) continue;            // block-uniform: tile fully masked
        const int t0 = tbs + w * 8;
        const int tl0 = t0 - tb;

        if (t0 < L) {
            // ---- A1: rolling 3-tap conv along t (8 steps), lane owns c-pair ----
            ushort* hw = h_s[w];
            float2 xm = {0.f, 0.f};
            if (t0 > 0) xm = *(const float2*)&xb[(size_t)(t0 - 1) * C_ + c2];
            float rm = rn_lds[tl0];
            float xnmx = xm.x * rm, xnmy = xm.y * rm;
            float2 xc = *(const float2*)&xb[(size_t)t0 * C_ + c2];
            float rc = rn_lds[tl0 + 1];
            float xncx = xc.x * rc, xncy = xc.y * rc;
#pragma unroll
            for (int tl = 0; tl < 8; ++tl) {
                int tn = t0 + tl + 1;
                float2 xp = {0.f, 0.f};
                if (tn < T_) xp = *(const float2*)&xb[(size_t)tn * C_ + c2];
                float rp = rn_lds[tl0 + tl + 2];
                float xnpx = xp.x * rp, xnpy = xp.y * rp;
                float hx = fmaxf(0.f, xnmx * wa.x + xncx * wb.x + xnpx * wc.x + sb.x);
                float hy = fmaxf(0.f, xnmy * wa.y + xncy * wb.y + xnpy * wc.y + sb.y);
                *(uint*)&hw[tl * 136 + c2] = pack2(hx, hy);
                xnmx = xncx; xnmy = xncy; xncx = xnpx; xncy = xnpy;
            }
            // ---- logits MFMA (w2 from LDS, 4 frags live at a time) ----
            f32x4 accL[4];
#pragma unroll
            for (int m = 0; m < 4; ++m) accL[m] = (f32x4){0.f, 0.f, 0.f, 0.f};
            const ushort* hb = hw + (fr & 7) * 136 + fg * 8;
#pragma unroll
            for (int q = 0; q < 4; ++q) {
                short8 hf = *(const short8*)(hb + q * 32);
                short8 w0 = *(const short8*)&w2l[((0 * 4 + q) * 64 + lane) * 8];
                short8 w1 = *(const short8*)&w2l[((1 * 4 + q) * 64 + lane) * 8];
                short8 w2f = *(const short8*)&w2l[((2 * 4 + q) * 64 + lane) * 8];
                short8 w3 = *(const short8*)&w2l[((3 * 4 + q) * 64 + lane) * 8];
                accL[0] = __builtin_amdgcn_mfma_f32_16x16x32_bf16(w0, hf, accL[0], 0, 0, 0);
                accL[1] = __builtin_amdgcn_mfma_f32_16x16x32_bf16(w1, hf, accL[1], 0, 0, 0);
                accL[2] = __builtin_amdgcn_mfma_f32_16x16x32_bf16(w2f, hf, accL[2], 0, 0, 0);
                accL[3] = __builtin_amdgcn_mfma_f32_16x16x32_bf16(w3, hf, accL[3], 0, 0, 0);
            }
            // ---- bn2 + relu + mask + softmax over k (lane column t = t0+fr, fr<8) ----
            if (fr < 8) {
                int t = t0 + fr;
                float v[16];
#pragma unroll
                for (int m = 0; m < 4; ++m)
#pragma unroll
                    for (int r = 0; r < 4; ++r)
                        v[m * 4 + r] = fmaxf(0.f, accL[m][r] + sh2r[m * 4 + r]);
                if (t < L) {
                    float mx = v[0];
#pragma unroll
                    for (int i = 1; i < 16; ++i) mx = fmaxf(mx, v[i]);
                    mx = fmaxf(mx, __shfl_xor(mx, 16, 64));
                    mx = fmaxf(mx, __shfl_xor(mx, 32, 64));
                    float se = 0.f;
#pragma unroll
                    for (int i = 0; i < 16; ++i) { v[i] = __expf(v[i] - mx); se += v[i]; }
                    se += __shfl_xor(se, 16, 64);
                    se += __shfl_xor(se, 32, 64);
                    float inv = 1.0f / se;
#pragma unroll
                    for (int i = 0; i < 16; ++i) v[i] *= inv;
                } else {
#pragma unroll
                    for (int i = 0; i < 16; ++i) v[i] = 0.015625f;
                }
#pragma unroll
                for (int m = 0; m < 4; ++m)
#pragma unroll
                    for (int r = 0; r < 4; ++r) {
                        int k = m * 16 + fg * 4 + r;
                        ((ushort*)&ab[buf][k * 5 + w])[fr] = (ushort)bfr(v[m * 4 + r]);
                    }
            }
        } else {
            // wave-masked within a live tile: a = 1/64 exactly
            uint4 ones;
            ones.x = ones.y = ones.z = ones.w = 0x3C803C80u;
            ab[buf][lane * 5 + w] = ones;
        }
        __syncthreads();
        // ---- copy-out a tile [64k][32t] (4 KB, fully coalesced) ----
        {
            uint4 v = ab[buf][(tid >> 2) * 5 + (tid & 3)];
            *((uint4*)(ag + (size_t)(tb / 32 + s) * 2048) + tid) = v;
        }
        buf ^= 1;
    }
}

// vlad GEMM: per (n, 256-t chunk): stage xn (x*rn -> bf16 t-minor LDS + ones
// row for asum), a fragments from global (or 1/64 constant when tile >= L),
// MFMA-accumulate, store private partials.
__global__ __launch_bounds__(256, 4) void vlad_k(
    const float* __restrict__ x, const int* __restrict__ length,
    float* __restrict__ ws) {

    __shared__ __align__(16) uint4 xn4[144 * 5];   // rows 0..127 xn, 128 ones, rest zero
    __shared__ float rn_lds[TCH];

    const int tid = threadIdx.x;
    const int lane = tid & 63;
    const int w = tid >> 6;
    const int fr = lane & 15, fg = lane >> 4;
    const int n = blockIdx.x >> 5;
    const int chunk = blockIdx.x & (NCH - 1);
    const int tb = chunk * TCH;
    const float* xb = x + (size_t)n * T_ * C_;
    const float* rng = ws + WS_RNORM + (size_t)n * T_;
    const int L = length[n];

    for (int i = tid; i < TCH; i += 256) rn_lds[i] = rng[tb + i];
    if (tid < 64) {
        int r = 128 + (tid >> 2), j = tid & 3;
        uint f = (r == 128) ? 0x3F803F80u : 0u;
        uint4 v; v.x = f; v.y = f; v.z = f; v.w = f;
        xn4[r * 5 + j] = v;
    }

    const ushort* ag = (const ushort*)(ws + WS_AG) + (size_t)n * T_ * K_;

    f32x4 accB[9];
#pragma unroll
    for (int cb = 0; cb < 9; ++cb) accB[cb] = (f32x4){0.f, 0.f, 0.f, 0.f};

    __syncthreads();

    for (int st = 0; st < TCH / 32; ++st) {
        const int t0 = tb + st * 32;
        const int tw = t0 + w * 8;
        // ---- stage xn t-minor (wave w owns t-slice w) ----
#pragma unroll
        for (int p = 0; p < 2; ++p) {
            const int c = lane + p * 64;
            uint pk[4];
#pragma unroll
            for (int tl = 0; tl < 8; ++tl) {
                float xv = xb[(size_t)(tw + tl) * C_ + c] * rn_lds[tw + tl - tb];
                uint b = bfr(xv);
                if (tl & 1) pk[tl >> 1] |= b << 16; else pk[tl >> 1] = b;
            }
            uint4 v4; v4.x = pk[0]; v4.y = pk[1]; v4.z = pk[2]; v4.w = pk[3];
            xn4[c * 5 + w] = v4;
        }
        __syncthreads();
        // ---- a fragment (global, or constant for fully-masked tile) + 9 MFMA ----
        short8 af;
        if (t0 < L) {
            af = *(const short8*)(ag + (size_t)(t0 >> 5) * 2048 + (w * 16 + fr) * 32 + fg * 8);
        } else {
#pragma unroll
            for (int j = 0; j < 8; ++j) af[j] = (short)0x3C80;
        }
#pragma unroll
        for (int cb = 0; cb < 9; ++cb) {
            short8 bfv = *(const short8*)&xn4[(cb * 16 + fr) * 5 + fg];
            accB[cb] = __builtin_amdgcn_mfma_f32_16x16x32_bf16(af, bfv, accB[cb], 0, 0, 0);
        }
        __syncthreads();
    }

    float* part = ws + WS_PART + (size_t)(n * NCH + chunk) * (K_ * C_);
#pragma unroll
    for (int cb = 0; cb < 8; ++cb)
#pragma unroll
        for (int r = 0; r < 4; ++r)
            part[(w * 16 + fg * 4 + r) * C_ + cb * 16 + fr] = accB[cb][r];
    if (fr == 0) {
#pragma unroll
        for (int r = 0; r < 4; ++r)
            atomicAdd(&ws[WS_ASUM + n * K_ + w * 16 + fg * 4 + r], accB[8][r]);
    }
}

// vlad[n][k][c] = sum over NCH per-chunk partials
__global__ void reduce_k(float* __restrict__ ws) {
    int idx = blockIdx.x * 256 + threadIdx.x;      // < N*K*C
    int n = idx >> 13;
    const float* p = ws + WS_PART + (size_t)n * NCH * (K_ * C_) + (idx & 8191);
    float s = 0.f;
#pragma unroll 8
    for (int b = 0; b < NCH; ++b) s += p[(size_t)b * (K_ * C_)];
    ws[WS_VLAD + idx] = s;
}

// per (n,k) row: subtract asum*centroid, intra-L2-normalize, accumulate gsum
__global__ void finalize_k(const float* __restrict__ cent, float* __restrict__ ws,
                           float* __restrict__ out) {
    int row = blockIdx.x * 4 + (threadIdx.x >> 6);  // n*64 + k
    int lane = threadIdx.x & 63;
    int n = row >> 6, k = row & 63;
    const float* v = ws + WS_VLAD + (size_t)row * C_;
    float as = ws[WS_ASUM + row];
    float y0 = v[lane] - as * cent[k * C_ + lane];
    float y1 = v[lane + 64] - as * cent[k * C_ + lane + 64];
    float ss = y0 * y0 + y1 * y1;
#pragma unroll
    for (int m = 1; m < 64; m <<= 1) ss += __shfl_xor(ss, m, 64);
    float rs = 1.0f / fmaxf(sqrtf(ss), 1e-12f);
    out[(size_t)row * C_ + lane] = y0 * rs;
    out[(size_t)row * C_ + lane + 64] = y1 * rs;
    if (lane == 0) atomicAdd(&ws[WS_GSUM + n], ss * rs * rs);
}

__global__ void gscale_k(float* __restrict__ out, const float* __restrict__ ws) {
    int idx = blockIdx.x * 256 + threadIdx.x;  // < N*K*C
    int n = idx >> 13;
    float g = ws[WS_GSUM + n];
    out[idx] *= 1.0f / fmaxf(sqrtf(g), 1e-12f);
}

extern "C" void kernel_launch(void* const* d_in, const int* in_sizes, int n_in,
                              void* d_out, int out_size, void* d_ws, size_t ws_size,
                              hipStream_t stream) {
    const float* x       = (const float*)d_in[0];
    const float* conv1_w = (const float*)d_in[1];
    const float* bn1_g   = (const float*)d_in[2];
    const float* bn1_b   = (const float*)d_in[3];
    const float* bn1_m   = (const float*)d_in[4];
    const float* bn1_v   = (const float*)d_in[5];
    const float* conv2_w = (const float*)d_in[6];
    const float* conv2_b = (const float*)d_in[7];
    const float* bn2_g   = (const float*)d_in[8];
    const float* bn2_b   = (const float*)d_in[9];
    const float* bn2_m   = (const float*)d_in[10];
    const float* bn2_v   = (const float*)d_in[11];
    const float* cent    = (const float*)d_in[12];
    const int*   length  = (const int*)d_in[13];
    float* out = (float*)d_out;
    float* ws  = (float*)d_ws;

    zero_ws<<<6, 256, 0, stream>>>(ws);
    setup_k<<<1, 256, 0, stream>>>(conv1_w, bn1_g, bn1_b, bn1_m, bn1_v,
                                   conv2_w, bn2_g, bn2_v, ws);
    rnorm_k<<<N_ * T_ / 4, 256, 0, stream>>>(x, ws);
    assign_k<<<N_ * BPN_A, 256, 0, stream>>>(x, conv2_b, bn2_g, bn2_b,
                                             bn2_m, bn2_v, length, ws);
    vlad_k<<<N_ * NCH, 256, 0, stream>>>(x, length, ws);
    reduce_k<<<(N_ * K_ * C_) / 256, 256, 0, stream>>>(ws);
    finalize_k<<<(N_ * K_) / 4, 256, 0, stream>>>(cent, ws, out);
    gscale_k<<<(N_ * K_ * C_) / 256, 256, 0, stream>>>(out, ws);
}

// Round 12
// 95.165 us; speedup vs baseline: 1.6751x; 1.0550x over previous
//
#include <hip/hip_runtime.h>
#include <math.h>

#define N_ 16
#define T_ 8192
#define C_ 128
#define K_ 64

#define TPB_A 128      // t per assign block
#define BPN_A 64       // assign blocks per n
#define TCH 256        // t per vlad block
#define NCH 32         // vlad chunks per n

// ---------------- OLD (fallback) ws layout in floats (34.63 MB) -------------
#define WS_VLAD 0
#define WS_ASUM 131072
#define WS_GSUM 132096
#define WS_ZEND 132608
#define WS_RNORM 132608
#define WS_W2F   263680
#define WS_P1    267776
#define WS_AG    268288
#define WS_PART  4462592       // -> 8656896 floats

// ---------------- NEW ws layout in floats (67.14 MB) ------------------------
#define NW_ASUM 0              // 1024
#define NW_GSUM 1024           // 16; zero region = [0, 2048)
#define NW_W2F  2048           // 4096 floats (8192 bf16)
#define NW_P1   6144           // 512 floats -> 6656, pad to 8192
#define NW_XTM  8192           // N*T*C bf16 = 8388608 floats -> 8396800
#define NW_AG   8396800        // N*T*K bf16 = 4194304 floats -> 12591104
#define NW_PART 12591104       // N*NCH*K*C  = 4194304 floats -> 16785408
#define NW_TOTAL 16785408

typedef __attribute__((ext_vector_type(8))) short short8;
typedef __attribute__((ext_vector_type(4))) float f32x4;

__device__ __forceinline__ uint bfr(float f) {          // fp32 -> bf16 (RNE)
    uint u = __float_as_uint(f);
    return (u + 0x7fffu + ((u >> 16) & 1u)) >> 16;
}
__device__ __forceinline__ uint pack2(float lo, float hi) {
    return bfr(lo) | (bfr(hi) << 16);
}
__device__ __forceinline__ float bfu(ushort u) {
    return __uint_as_float(((uint)u) << 16);
}

__global__ void zero_k(float* p, int cnt) {
    int i = blockIdx.x * 256 + threadIdx.x;
    if (i < cnt) p[i] = 0.0f;
}

// Precompute constant tables (parameterized destinations; shared by both paths)
__global__ void setup_k(const float* __restrict__ conv1_w,
                        const float* __restrict__ bn1_g, const float* __restrict__ bn1_b,
                        const float* __restrict__ bn1_m, const float* __restrict__ bn1_v,
                        const float* __restrict__ conv2_w,
                        const float* __restrict__ bn2_g, const float* __restrict__ bn2_v,
                        ushort* __restrict__ w2t, float* __restrict__ p1) {
    const int tid = threadIdx.x;
    for (int idx = tid; idx < 8192; idx += 256) {
        int j = idx & 7;
        int lane = (idx >> 3) & 63;
        int mq = idx >> 9;
        int m = mq >> 2, q = mq & 3;
        int fr = lane & 15, fg = lane >> 4;
        int k = m * 16 + fr;
        float sck = bn2_g[k] * rsqrtf(bn2_v[k] + 1e-5f);
        float v = conv2_w[k * C_ + q * 32 + fg * 8 + j] * sck;
        w2t[idx] = (ushort)bfr(v);
    }
    for (int c = tid; c < C_; c += 256) {
        float s1 = bn1_g[c] * rsqrtf(bn1_v[c] + 1e-5f);
        p1[c]       = conv1_w[c * 9 + 1] * s1;
        p1[128 + c] = conv1_w[c * 9 + 4] * s1;
        p1[256 + c] = conv1_w[c * 9 + 7] * s1;
        p1[384 + c] = bn1_b[c] - bn1_m[c] * s1;
    }
}

// ================= NEW PATH =================================================

// Normalize rows and emit xn bf16 in t-minor chunks [chunk=32t][128c][32t].
__global__ __launch_bounds__(256, 8) void xnorm_k(const float* __restrict__ x,
                                                  ushort* __restrict__ xtm) {
    __shared__ uint xt[32][64];            // packed c-pairs, [t][c2]
    const int tid = threadIdx.x;
    const int lane = tid & 63;
    const int w = tid >> 6;
    const size_t row0 = (size_t)blockIdx.x * 32;

#pragma unroll
    for (int i = 0; i < 8; ++i) {
        int r = w * 8 + i;
        const float* xr = x + (row0 + r) * C_;
        float2 v = *(const float2*)&xr[lane * 2];
        float ss = v.x * v.x + v.y * v.y;
#pragma unroll
        for (int m = 1; m < 64; m <<= 1) ss += __shfl_xor(ss, m, 64);
        float rn = 1.0f / fmaxf(sqrtf(ss), 1e-12f);
        xt[r][lane] = pack2(v.x * rn, v.y * rn);
    }
    __syncthreads();

    uint4* dst = (uint4*)(xtm + (size_t)blockIdx.x * 4096);
#pragma unroll
    for (int uu = 0; uu < 2; ++uu) {
        int u = tid * 2 + uu;              // 0..511
        int c = u >> 2, j = u & 3;
        int cw = c >> 1, sh = (c & 1) * 16;
        uint o[4];
#pragma unroll
        for (int q = 0; q < 4; ++q) {
            uint lo = (xt[j * 8 + q * 2][cw] >> sh) & 0xffffu;
            uint hi = (xt[j * 8 + q * 2 + 1][cw] >> sh) & 0xffffu;
            o[q] = lo | (hi << 16);
        }
        uint4 v; v.x = o[0]; v.y = o[1]; v.z = o[2]; v.w = o[3];
        dst[u] = v;
    }
}

// a-production from xn bf16: conv in registers over 8-t vectors -> logits MFMA
// -> softmax -> a tiles [64k][32t]. Fully-masked super-tiles skipped.
__global__ __launch_bounds__(256, 3) void assign2_k(
    const ushort* __restrict__ xtm,
    const float* __restrict__ conv2_b,
    const float* __restrict__ bn2_g, const float* __restrict__ bn2_b,
    const float* __restrict__ bn2_m, const float* __restrict__ bn2_v,
    const int* __restrict__ length,
    const ushort* __restrict__ w2t, const float* __restrict__ p1,
    ushort* __restrict__ agall) {

    __shared__ __align__(16) ushort w2l[8192];
    __shared__ __align__(16) ushort h_s[4][8 * 136];
    __shared__ __align__(16) uint4 ab[2][64 * 5];

    const int tid = threadIdx.x;
    const int lane = tid & 63;
    const int w = tid >> 6;
    const int fr = lane & 15, fg = lane >> 4;
    const int n = blockIdx.x >> 6;
    const int tb = (blockIdx.x & (BPN_A - 1)) * TPB_A;
    const ushort* xtm_n = xtm + (size_t)n * 256 * 4096;
    const int L = length[n];

    {
        const uint4* w2g = (const uint4*)w2t;
        uint4* w2d = (uint4*)w2l;
#pragma unroll
        for (int i = 0; i < 4; ++i) w2d[tid + i * 256] = w2g[tid + i * 256];
    }

    // conv1/bn1 folded params for c = lane, lane+64
    float wa[2], wbv[2], wcv[2], sbv[2];
#pragma unroll
    for (int p = 0; p < 2; ++p) {
        int c = lane + p * 64;
        wa[p] = p1[c]; wbv[p] = p1[128 + c];
        wcv[p] = p1[256 + c]; sbv[p] = p1[384 + c];
    }

    float sh2r[16];
#pragma unroll
    for (int m = 0; m < 4; ++m)
#pragma unroll
        for (int r = 0; r < 4; ++r) {
            int k = m * 16 + fg * 4 + r;
            float s = bn2_g[k] * rsqrtf(bn2_v[k] + 1e-5f);
            sh2r[m * 4 + r] = s * conv2_b[k] + bn2_b[k] - bn2_m[k] * s;
        }

    ushort* ag = agall + (size_t)n * (T_ / 32) * 2048;
    int buf = 0;
    __syncthreads();

    for (int s = 0; s < TPB_A / 32; ++s) {
        const int tbs = tb + s * 32;
        if (tbs >= L) continue;            // block-uniform skip
        const int tc = tbs >> 5;
        const ushort* xch = xtm_n + (size_t)tc * 4096;
        const int t0 = tbs + w * 8;

        if (t0 < L) {
            // ---- A1: conv from bf16 xn chunks, in registers ----
            ushort* hw = h_s[w];
#pragma unroll
            for (int p = 0; p < 2; ++p) {
                const int c = lane + p * 64;
                short8 xv8 = *(const short8*)&xch[c * 32 + w * 8];
                float xm1 = 0.f, xp8 = 0.f;
                if (t0 > 0)
                    xm1 = bfu(w > 0 ? xch[c * 32 + w * 8 - 1]
                                    : xch[c * 32 + 31 - 4096]);
                if (t0 + 8 < T_)
                    xp8 = bfu(w < 3 ? xch[c * 32 + w * 8 + 8]
                                    : xch[c * 32 + 4096]);
                float a0 = bfu((ushort)xv8[0]), a1 = bfu((ushort)xv8[1]);
                float a2 = bfu((ushort)xv8[2]), a3 = bfu((ushort)xv8[3]);
                float a4 = bfu((ushort)xv8[4]), a5 = bfu((ushort)xv8[5]);
                float a6 = bfu((ushort)xv8[6]), a7 = bfu((ushort)xv8[7]);
                float WA = wa[p], WB = wbv[p], WC = wcv[p], SB = sbv[p];
                hw[0 * 136 + c] = (ushort)bfr(fmaxf(0.f, xm1 * WA + a0 * WB + a1 * WC + SB));
                hw[1 * 136 + c] = (ushort)bfr(fmaxf(0.f, a0 * WA + a1 * WB + a2 * WC + SB));
                hw[2 * 136 + c] = (ushort)bfr(fmaxf(0.f, a1 * WA + a2 * WB + a3 * WC + SB));
                hw[3 * 136 + c] = (ushort)bfr(fmaxf(0.f, a2 * WA + a3 * WB + a4 * WC + SB));
                hw[4 * 136 + c] = (ushort)bfr(fmaxf(0.f, a3 * WA + a4 * WB + a5 * WC + SB));
                hw[5 * 136 + c] = (ushort)bfr(fmaxf(0.f, a4 * WA + a5 * WB + a6 * WC + SB));
                hw[6 * 136 + c] = (ushort)bfr(fmaxf(0.f, a5 * WA + a6 * WB + a7 * WC + SB));
                hw[7 * 136 + c] = (ushort)bfr(fmaxf(0.f, a6 * WA + a7 * WB + xp8 * WC + SB));
            }
            // ---- logits MFMA (w2 from LDS) ----
            f32x4 accL[4];
#pragma unroll
            for (int m = 0; m < 4; ++m) accL[m] = (f32x4){0.f, 0.f, 0.f, 0.f};
            const ushort* hb = h_s[w] + (fr & 7) * 136 + fg * 8;
#pragma unroll
            for (int q = 0; q < 4; ++q) {
                short8 hf = *(const short8*)(hb + q * 32);
                short8 w0 = *(const short8*)&w2l[((0 * 4 + q) * 64 + lane) * 8];
                short8 w1 = *(const short8*)&w2l[((1 * 4 + q) * 64 + lane) * 8];
                short8 w2f = *(const short8*)&w2l[((2 * 4 + q) * 64 + lane) * 8];
                short8 w3 = *(const short8*)&w2l[((3 * 4 + q) * 64 + lane) * 8];
                accL[0] = __builtin_amdgcn_mfma_f32_16x16x32_bf16(w0, hf, accL[0], 0, 0, 0);
                accL[1] = __builtin_amdgcn_mfma_f32_16x16x32_bf16(w1, hf, accL[1], 0, 0, 0);
                accL[2] = __builtin_amdgcn_mfma_f32_16x16x32_bf16(w2f, hf, accL[2], 0, 0, 0);
                accL[3] = __builtin_amdgcn_mfma_f32_16x16x32_bf16(w3, hf, accL[3], 0, 0, 0);
            }
            // ---- bn2 + relu + mask + softmax over k (lane column t = t0+fr, fr<8) ----
            if (fr < 8) {
                int t = t0 + fr;
                float v[16];
#pragma unroll
                for (int m = 0; m < 4; ++m)
#pragma unroll
                    for (int r = 0; r < 4; ++r)
                        v[m * 4 + r] = fmaxf(0.f, accL[m][r] + sh2r[m * 4 + r]);
                if (t < L) {
                    float mx = v[0];
#pragma unroll
                    for (int i = 1; i < 16; ++i) mx = fmaxf(mx, v[i]);
                    mx = fmaxf(mx, __shfl_xor(mx, 16, 64));
                    mx = fmaxf(mx, __shfl_xor(mx, 32, 64));
                    float se = 0.f;
#pragma unroll
                    for (int i = 0; i < 16; ++i) { v[i] = __expf(v[i] - mx); se += v[i]; }
                    se += __shfl_xor(se, 16, 64);
                    se += __shfl_xor(se, 32, 64);
                    float inv = 1.0f / se;
#pragma unroll
                    for (int i = 0; i < 16; ++i) v[i] *= inv;
                } else {
#pragma unroll
                    for (int i = 0; i < 16; ++i) v[i] = 0.015625f;
                }
#pragma unroll
                for (int m = 0; m < 4; ++m)
#pragma unroll
                    for (int r = 0; r < 4; ++r) {
                        int k = m * 16 + fg * 4 + r;
                        ((ushort*)&ab[buf][k * 5 + w])[fr] = (ushort)bfr(v[m * 4 + r]);
                    }
            }
        } else {
            uint4 ones;
            ones.x = ones.y = ones.z = ones.w = 0x3C803C80u;
            ab[buf][lane * 5 + w] = ones;
        }
        __syncthreads();
        {
            uint4 v = ab[buf][(tid >> 2) * 5 + (tid & 3)];
            *((uint4*)(ag + (size_t)(tb / 32 + s) * 2048) + tid) = v;
        }
        buf ^= 1;
    }
}

// barrier-free vlad GEMM: A-fragments from ag, B-fragments from xtm, both
// perfectly coalesced global loads; asum via register ones-fragment.
__global__ __launch_bounds__(256, 4) void vlad2_k(
    const ushort* __restrict__ xtm, const ushort* __restrict__ agall,
    const int* __restrict__ length, float* __restrict__ part,
    float* __restrict__ asum) {

    const int tid = threadIdx.x;
    const int lane = tid & 63;
    const int w = tid >> 6;
    const int fr = lane & 15, fg = lane >> 4;
    const int n = blockIdx.x >> 5;
    const int chunk = blockIdx.x & (NCH - 1);
    const int tb = chunk * TCH;
    const ushort* xn_n = xtm + (size_t)n * 256 * 4096;
    const ushort* ag = agall + (size_t)n * (T_ / 32) * 2048;
    const int L = length[n];

    short8 onesf;
    {
        short f = (fr == 0) ? (short)0x3F80 : (short)0;
#pragma unroll
        for (int j = 0; j < 8; ++j) onesf[j] = f;
    }

    f32x4 accB[9];
#pragma unroll
    for (int cb = 0; cb < 9; ++cb) accB[cb] = (f32x4){0.f, 0.f, 0.f, 0.f};

#pragma unroll
    for (int st = 0; st < TCH / 32; ++st) {
        const int t0 = tb + st * 32;
        const int tc = t0 >> 5;
        short8 af;
        if (t0 < L) {
            af = *(const short8*)(ag + (size_t)tc * 2048 + (w * 16 + fr) * 32 + fg * 8);
        } else {
#pragma unroll
            for (int j = 0; j < 8; ++j) af[j] = (short)0x3C80;
        }
        const ushort* xch = xn_n + (size_t)tc * 4096;
#pragma unroll
        for (int cb = 0; cb < 8; ++cb) {
            short8 bfv = *(const short8*)&xch[(cb * 16 + fr) * 32 + fg * 8];
            accB[cb] = __builtin_amdgcn_mfma_f32_16x16x32_bf16(af, bfv, accB[cb], 0, 0, 0);
        }
        accB[8] = __builtin_amdgcn_mfma_f32_16x16x32_bf16(af, onesf, accB[8], 0, 0, 0);
    }

    float* pr = part + (size_t)(n * NCH + chunk) * (K_ * C_);
#pragma unroll
    for (int cb = 0; cb < 8; ++cb)
#pragma unroll
        for (int r = 0; r < 4; ++r)
            pr[(w * 16 + fg * 4 + r) * C_ + cb * 16 + fr] = accB[cb][r];
    if (fr == 0) {
#pragma unroll
        for (int r = 0; r < 4; ++r)
            atomicAdd(&asum[n * K_ + w * 16 + fg * 4 + r], accB[8][r]);
    }
}

// fused reduce + finalize: sum 32 partials, subtract asum*centroid, intra-norm
__global__ void finalize2_k(const float* __restrict__ cent,
                            const float* __restrict__ part,
                            const float* __restrict__ asum,
                            float* __restrict__ gsum, float* __restrict__ out) {
    int row = blockIdx.x * 4 + (threadIdx.x >> 6);  // n*64 + k
    int lane = threadIdx.x & 63;
    int n = row >> 6, k = row & 63;
    const float* pr = part + (size_t)n * NCH * (K_ * C_) + k * C_;
    float y0 = 0.f, y1 = 0.f;
#pragma unroll 8
    for (int b = 0; b < NCH; ++b) {
        y0 += pr[(size_t)b * (K_ * C_) + lane];
        y1 += pr[(size_t)b * (K_ * C_) + lane + 64];
    }
    float as = asum[row];
    y0 -= as * cent[k * C_ + lane];
    y1 -= as * cent[k * C_ + lane + 64];
    float ss = y0 * y0 + y1 * y1;
#pragma unroll
    for (int m = 1; m < 64; m <<= 1) ss += __shfl_xor(ss, m, 64);
    float rs = 1.0f / fmaxf(sqrtf(ss), 1e-12f);
    out[(size_t)row * C_ + lane] = y0 * rs;
    out[(size_t)row * C_ + lane + 64] = y1 * rs;
    if (lane == 0) atomicAdd(&gsum[n], ss * rs * rs);
}

__global__ void gscale2_k(float* __restrict__ out, const float* __restrict__ gsum) {
    int idx = blockIdx.x * 256 + threadIdx.x;
    int n = idx >> 13;
    out[idx] *= 1.0f / fmaxf(sqrtf(gsum[n]), 1e-12f);
}

// ================= OLD (fallback) PATH — proven round-11 kernels ============

__global__ void rnorm_k(const float* __restrict__ x, float* __restrict__ ws) {
    int row = blockIdx.x * 4 + (threadIdx.x >> 6);
    int lane = threadIdx.x & 63;
    const float* xr = x + (size_t)row * C_;
    float a = xr[lane], b = xr[lane + 64];
    float ss = a * a + b * b;
#pragma unroll
    for (int m = 1; m < 64; m <<= 1) ss += __shfl_xor(ss, m, 64);
    if (lane == 0) ws[WS_RNORM + row] = 1.0f / fmaxf(sqrtf(ss), 1e-12f);
}

__global__ __launch_bounds__(256, 3) void assign_k(
    const float* __restrict__ x,
    const float* __restrict__ conv2_b,
    const float* __restrict__ bn2_g, const float* __restrict__ bn2_b,
    const float* __restrict__ bn2_m, const float* __restrict__ bn2_v,
    const int* __restrict__ length,
    float* __restrict__ ws) {

    __shared__ __align__(16) ushort w2l[8192];
    __shared__ __align__(16) ushort h_s[4][8 * 136];
    __shared__ __align__(16) uint4 ab[2][64 * 5];
    __shared__ float rn_lds[TPB_A + 2];

    const int tid = threadIdx.x;
    const int lane = tid & 63;
    const int w = tid >> 6;
    const int fr = lane & 15, fg = lane >> 4;
    const int n = blockIdx.x >> 6;
    const int tb = (blockIdx.x & (BPN_A - 1)) * TPB_A;
    const float* xb = x + (size_t)n * T_ * C_;
    const float* rng = ws + WS_RNORM + (size_t)n * T_;
    const int L = length[n];

    {
        const uint4* w2g = (const uint4*)(ws + WS_W2F);
        uint4* w2d = (uint4*)w2l;
#pragma unroll
        for (int i = 0; i < 4; ++i) w2d[tid + i * 256] = w2g[tid + i * 256];
    }
    for (int i = tid; i < TPB_A + 2; i += 256) {
        int t = tb - 1 + i;
        rn_lds[i] = (t >= 0 && t < T_) ? rng[t] : 0.f;
    }

    const int c2 = lane * 2;
    float2 wa = *(const float2*)&ws[WS_P1 + c2];
    float2 wb = *(const float2*)&ws[WS_P1 + 128 + c2];
    float2 wc = *(const float2*)&ws[WS_P1 + 256 + c2];
    float2 sb = *(const float2*)&ws[WS_P1 + 384 + c2];

    float sh2r[16];
#pragma unroll
    for (int m = 0; m < 4; ++m)
#pragma unroll
        for (int r = 0; r < 4; ++r) {
            int k = m * 16 + fg * 4 + r;
            float s = bn2_g[k] * rsqrtf(bn2_v[k] + 1e-5f);
            sh2r[m * 4 + r] = s * conv2_b[k] + bn2_b[k] - bn2_m[k] * s;
        }

    ushort* ag = (ushort*)(ws + WS_AG) + (size_t)n * T_ * K_;
    int buf = 0;
    __syncthreads();

    for (int s = 0; s < TPB_A / 32; ++s) {
        const int tbs = tb + s * 32;
        if (tbs >= L) continue;
        const int t0 = tbs + w * 8;
        const int tl0 = t0 - tb;

        if (t0 < L) {
            ushort* hw = h_s[w];
            float2 xm = {0.f, 0.f};
            if (t0 > 0) xm = *(const float2*)&xb[(size_t)(t0 - 1) * C_ + c2];
            float rm = rn_lds[tl0];
            float xnmx = xm.x * rm, xnmy = xm.y * rm;
            float2 xc = *(const float2*)&xb[(size_t)t0 * C_ + c2];
            float rc = rn_lds[tl0 + 1];
            float xncx = xc.x * rc, xncy = xc.y * rc;
#pragma unroll
            for (int tl = 0; tl < 8; ++tl) {
                int tn = t0 + tl + 1;
                float2 xp = {0.f, 0.f};
                if (tn < T_) xp = *(const float2*)&xb[(size_t)tn * C_ + c2];
                float rp = rn_lds[tl0 + tl + 2];
                float xnpx = xp.x * rp, xnpy = xp.y * rp;
                float hx = fmaxf(0.f, xnmx * wa.x + xncx * wb.x + xnpx * wc.x + sb.x);
                float hy = fmaxf(0.f, xnmy * wa.y + xncy * wb.y + xnpy * wc.y + sb.y);
                *(uint*)&hw[tl * 136 + c2] = pack2(hx, hy);
                xnmx = xncx; xnmy = xncy; xncx = xnpx; xncy = xnpy;
            }
            f32x4 accL[4];
#pragma unroll
            for (int m = 0; m < 4; ++m) accL[m] = (f32x4){0.f, 0.f, 0.f, 0.f};
            const ushort* hb = hw + (fr & 7) * 136 + fg * 8;
#pragma unroll
            for (int q = 0; q < 4; ++q) {
                short8 hf = *(const short8*)(hb + q * 32);
                short8 w0 = *(const short8*)&w2l[((0 * 4 + q) * 64 + lane) * 8];
                short8 w1 = *(const short8*)&w2l[((1 * 4 + q) * 64 + lane) * 8];
                short8 w2f = *(const short8*)&w2l[((2 * 4 + q) * 64 + lane) * 8];
                short8 w3 = *(const short8*)&w2l[((3 * 4 + q) * 64 + lane) * 8];
                accL[0] = __builtin_amdgcn_mfma_f32_16x16x32_bf16(w0, hf, accL[0], 0, 0, 0);
                accL[1] = __builtin_amdgcn_mfma_f32_16x16x32_bf16(w1, hf, accL[1], 0, 0, 0);
                accL[2] = __builtin_amdgcn_mfma_f32_16x16x32_bf16(w2f, hf, accL[2], 0, 0, 0);
                accL[3] = __builtin_amdgcn_mfma_f32_16x16x32_bf16(w3, hf, accL[3], 0, 0, 0);
            }
            if (fr < 8) {
                int t = t0 + fr;
                float v[16];
#pragma unroll
                for (int m = 0; m < 4; ++m)
#pragma unroll
                    for (int r = 0; r < 4; ++r)
                        v[m * 4 + r] = fmaxf(0.f, accL[m][r] + sh2r[m * 4 + r]);
                if (t < L) {
                    float mx = v[0];
#pragma unroll
                    for (int i = 1; i < 16; ++i) mx = fmaxf(mx, v[i]);
                    mx = fmaxf(mx, __shfl_xor(mx, 16, 64));
                    mx = fmaxf(mx, __shfl_xor(mx, 32, 64));
                    float se = 0.f;
#pragma unroll
                    for (int i = 0; i < 16; ++i) { v[i] = __expf(v[i] - mx); se += v[i]; }
                    se += __shfl_xor(se, 16, 64);
                    se += __shfl_xor(se, 32, 64);
                    float inv = 1.0f / se;
#pragma unroll
                    for (int i = 0; i < 16; ++i) v[i] *= inv;
                } else {
#pragma unroll
                    for (int i = 0; i < 16; ++i) v[i] = 0.015625f;
                }
#pragma unroll
                for (int m = 0; m < 4; ++m)
#pragma unroll
                    for (int r = 0; r < 4; ++r) {
                        int k = m * 16 + fg * 4 + r;
                        ((ushort*)&ab[buf][k * 5 + w])[fr] = (ushort)bfr(v[m * 4 + r]);
                    }
            }
        } else {
            uint4 ones;
            ones.x = ones.y = ones.z = ones.w = 0x3C803C80u;
            ab[buf][lane * 5 + w] = ones;
        }
        __syncthreads();
        {
            uint4 v = ab[buf][(tid >> 2) * 5 + (tid & 3)];
            *((uint4*)(ag + (size_t)(tb / 32 + s) * 2048) + tid) = v;
        }
        buf ^= 1;
    }
}

__global__ __launch_bounds__(256, 4) void vlad_k(
    const float* __restrict__ x, const int* __restrict__ length,
    float* __restrict__ ws) {

    __shared__ __align__(16) uint4 xn4[144 * 5];
    __shared__ float rn_lds[TCH];

    const int tid = threadIdx.x;
    const int lane = tid & 63;
    const int w = tid >> 6;
    const int fr = lane & 15, fg = lane >> 4;
    const int n = blockIdx.x >> 5;
    const int chunk = blockIdx.x & (NCH - 1);
    const int tb = chunk * TCH;
    const float* xb = x + (size_t)n * T_ * C_;
    const float* rng = ws + WS_RNORM + (size_t)n * T_;
    const int L = length[n];

    for (int i = tid; i < TCH; i += 256) rn_lds[i] = rng[tb + i];
    if (tid < 64) {
        int r = 128 + (tid >> 2), j = tid & 3;
        uint f = (r == 128) ? 0x3F803F80u : 0u;
        uint4 v; v.x = f; v.y = f; v.z = f; v.w = f;
        xn4[r * 5 + j] = v;
    }

    const ushort* ag = (const ushort*)(ws + WS_AG) + (size_t)n * T_ * K_;

    f32x4 accB[9];
#pragma unroll
    for (int cb = 0; cb < 9; ++cb) accB[cb] = (f32x4){0.f, 0.f, 0.f, 0.f};

    __syncthreads();

    for (int st = 0; st < TCH / 32; ++st) {
        const int t0 = tb + st * 32;
        const int tw = t0 + w * 8;
#pragma unroll
        for (int p = 0; p < 2; ++p) {
            const int c = lane + p * 64;
            uint pk[4];
#pragma unroll
            for (int tl = 0; tl < 8; ++tl) {
                float xv = xb[(size_t)(tw + tl) * C_ + c] * rn_lds[tw + tl - tb];
                uint b = bfr(xv);
                if (tl & 1) pk[tl >> 1] |= b << 16; else pk[tl >> 1] = b;
            }
            uint4 v4; v4.x = pk[0]; v4.y = pk[1]; v4.z = pk[2]; v4.w = pk[3];
            xn4[c * 5 + w] = v4;
        }
        __syncthreads();
        short8 af;
        if (t0 < L) {
            af = *(const short8*)(ag + (size_t)(t0 >> 5) * 2048 + (w * 16 + fr) * 32 + fg * 8);
        } else {
#pragma unroll
            for (int j = 0; j < 8; ++j) af[j] = (short)0x3C80;
        }
#pragma unroll
        for (int cb = 0; cb < 9; ++cb) {
            short8 bfv = *(const short8*)&xn4[(cb * 16 + fr) * 5 + fg];
            accB[cb] = __builtin_amdgcn_mfma_f32_16x16x32_bf16(af, bfv, accB[cb], 0, 0, 0);
        }
        __syncthreads();
    }

    float* part = ws + WS_PART + (size_t)(n * NCH + chunk) * (K_ * C_);
#pragma unroll
    for (int cb = 0; cb < 8; ++cb)
#pragma unroll
        for (int r = 0; r < 4; ++r)
            part[(w * 16 + fg * 4 + r) * C_ + cb * 16 + fr] = accB[cb][r];
    if (fr == 0) {
#pragma unroll
        for (int r = 0; r < 4; ++r)
            atomicAdd(&ws[WS_ASUM + n * K_ + w * 16 + fg * 4 + r], accB[8][r]);
    }
}

__global__ void reduce_k(float* __restrict__ ws) {
    int idx = blockIdx.x * 256 + threadIdx.x;
    int n = idx >> 13;
    const float* p = ws + WS_PART + (size_t)n * NCH * (K_ * C_) + (idx & 8191);
    float s = 0.f;
#pragma unroll 8
    for (int b = 0; b < NCH; ++b) s += p[(size_t)b * (K_ * C_)];
    ws[WS_VLAD + idx] = s;
}

__global__ void finalize_k(const float* __restrict__ cent, float* __restrict__ ws,
                           float* __restrict__ out) {
    int row = blockIdx.x * 4 + (threadIdx.x >> 6);
    int lane = threadIdx.x & 63;
    int n = row >> 6, k = row & 63;
    const float* v = ws + WS_VLAD + (size_t)row * C_;
    float as = ws[WS_ASUM + row];
    float y0 = v[lane] - as * cent[k * C_ + lane];
    float y1 = v[lane + 64] - as * cent[k * C_ + lane + 64];
    float ss = y0 * y0 + y1 * y1;
#pragma unroll
    for (int m = 1; m < 64; m <<= 1) ss += __shfl_xor(ss, m, 64);
    float rs = 1.0f / fmaxf(sqrtf(ss), 1e-12f);
    out[(size_t)row * C_ + lane] = y0 * rs;
    out[(size_t)row * C_ + lane + 64] = y1 * rs;
    if (lane == 0) atomicAdd(&ws[WS_GSUM + n], ss * rs * rs);
}

extern "C" void kernel_launch(void* const* d_in, const int* in_sizes, int n_in,
                              void* d_out, int out_size, void* d_ws, size_t ws_size,
                              hipStream_t stream) {
    const float* x       = (const float*)d_in[0];
    const float* conv1_w = (const float*)d_in[1];
    const float* bn1_g   = (const float*)d_in[2];
    const float* bn1_b   = (const float*)d_in[3];
    const float* bn1_m   = (const float*)d_in[4];
    const float* bn1_v   = (const float*)d_in[5];
    const float* conv2_w = (const float*)d_in[6];
    const float* conv2_b = (const float*)d_in[7];
    const float* bn2_g   = (const float*)d_in[8];
    const float* bn2_b   = (const float*)d_in[9];
    const float* bn2_m   = (const float*)d_in[10];
    const float* bn2_v   = (const float*)d_in[11];
    const float* cent    = (const float*)d_in[12];
    const int*   length  = (const int*)d_in[13];
    float* out = (float*)d_out;
    float* ws  = (float*)d_ws;

    if (ws_size >= (size_t)NW_TOTAL * 4) {
        // -------- NEW PATH --------
        zero_k<<<8, 256, 0, stream>>>(ws, 2048);
        setup_k<<<1, 256, 0, stream>>>(conv1_w, bn1_g, bn1_b, bn1_m, bn1_v,
                                       conv2_w, bn2_g, bn2_v,
                                       (ushort*)(ws + NW_W2F), ws + NW_P1);
        xnorm_k<<<N_ * T_ / 32, 256, 0, stream>>>(x, (ushort*)(ws + NW_XTM));
        assign2_k<<<N_ * BPN_A, 256, 0, stream>>>(
            (const ushort*)(ws + NW_XTM), conv2_b, bn2_g, bn2_b, bn2_m, bn2_v,
            length, (const ushort*)(ws + NW_W2F), ws + NW_P1,
            (ushort*)(ws + NW_AG));
        vlad2_k<<<N_ * NCH, 256, 0, stream>>>(
            (const ushort*)(ws + NW_XTM), (const ushort*)(ws + NW_AG),
            length, ws + NW_PART, ws + NW_ASUM);
        finalize2_k<<<(N_ * K_) / 4, 256, 0, stream>>>(
            cent, ws + NW_PART, ws + NW_ASUM, ws + NW_GSUM, out);
        gscale2_k<<<(N_ * K_ * C_) / 256, 256, 0, stream>>>(out, ws + NW_GSUM);
    } else {
        // -------- OLD (proven round-11) PATH --------
        zero_k<<<6, 256, 0, stream>>>(ws + WS_ASUM, WS_ZEND - WS_ASUM);
        setup_k<<<1, 256, 0, stream>>>(conv1_w, bn1_g, bn1_b, bn1_m, bn1_v,
                                       conv2_w, bn2_g, bn2_v,
                                       (ushort*)(ws + WS_W2F), ws + WS_P1);
        rnorm_k<<<N_ * T_ / 4, 256, 0, stream>>>(x, ws);
        assign_k<<<N_ * BPN_A, 256, 0, stream>>>(x, conv2_b, bn2_g, bn2_b,
                                                 bn2_m, bn2_v, length, ws);
        vlad_k<<<N_ * NCH, 256, 0, stream>>>(x, length, ws);
        reduce_k<<<(N_ * K_ * C_) / 256, 256, 0, stream>>>(ws);
        finalize_k<<<(N_ * K_) / 4, 256, 0, stream>>>(cent, ws, out);
        gscale2_k<<<(N_ * K_ * C_) / 256, 256, 0, stream>>>(out, ws + WS_GSUM);
    }
}